// Round 8
// baseline (165.604 us; speedup 1.0000x reference)
//
#include <hip/hip_runtime.h>
#include <math.h>

// Problem constants
#define BATCH 8
#define NVERT 8192
#define NPD   64
#define NCELL 4096             // 64*64 grid cells per batch
#define SPLITS 64              // blocks per batch
#define JPB   (NVERT / SPLITS) // 128 vertices per block
#define G     16               // vertices staged per round
#define ROUNDS (JPB / G)       // 8
#define MAGIC  0x5A17C0DEu     // != 0xAAAAAAAA poison, != 0

#ifndef M_PI
#define M_PI 3.14159265358979323846
#endif

// ws layout (floats / uints)
#define TOTPART_OFF  0         // float totpart[512]
#define FLAGS_OFF    1024      // uint  flags[512]
#define PARTIALS_OFF 4096      // float partials[512*4096] = 8 MB

static __device__ __forceinline__ float fast_exp2(float x) {
#if __has_builtin(__builtin_amdgcn_exp2f)
    return __builtin_amdgcn_exp2f(x);
#else
    return exp2f(x);
#endif
}

// ---------------------------------------------------------------------------
// Single dispatch: sigma + separable KDE + block partial + flag handshake +
// distributed finish. Grid = BATCH*SPLITS = 512 blocks x 256 threads
// (4 waves; ~34 KB LDS -> 4 blocks/CU capacity, 2/CU resident => all 512
// co-resident, so the intra-batch flag spin cannot deadlock).
// Phase 3: block (b,sp) finishes cells [sp*64, sp*64+63] of batch b.
// ---------------------------------------------------------------------------
__global__ __launch_bounds__(256) void kde_one(const float* __restrict__ T,
                                               float* __restrict__ totpart,
                                               unsigned int* __restrict__ flags,
                                               float* __restrict__ partials,
                                               float* __restrict__ out) {
    const int b   = blockIdx.x >> 6;           // / SPLITS
    const int sp  = blockIdx.x & (SPLITS - 1);
    const int j0  = sp * JPB;
    const int tid = threadIdx.x;
    const int w    = tid >> 6;                 // wave id 0..3
    const int lane = tid & 63;

    __shared__ float  smem_es[2 * G * 128];   // 16 KB; aliased as gA in epilogue
    __shared__ float  gB[NCELL];              // 16 KB
    __shared__ float2 tj[JPB];                // this block's vertex slice
    __shared__ float  red[4][4];
    __shared__ float  fin[4][64];             // phase-3 per-wave strip sums
    __shared__ float  bcast[2];               // kexp2, scale
    float* gA = smem_es;

    // ---- phase 0: sigma over the full batch (redundant per block) ----
    const float4* T4 = reinterpret_cast<const float4*>(T + (size_t)b * NVERT * 2);
    float sx = 0.f, sx2 = 0.f, sy = 0.f, sy2 = 0.f;
    for (int q = tid; q < NVERT / 2; q += 256) {   // 2 vertices per float4
        float4 v = T4[q];
        sx += v.x + v.z;
        sy += v.y + v.w;
        sx2 += v.x * v.x + v.z * v.z;
        sy2 += v.y * v.y + v.w * v.w;
        int local = 2 * q - j0;                    // even when in range
        if ((unsigned)local < (unsigned)JPB)
            *reinterpret_cast<float4*>(&tj[local]) = v;
    }
    for (int off = 32; off; off >>= 1) {
        sx  += __shfl_down(sx,  off);  sx2 += __shfl_down(sx2, off);
        sy  += __shfl_down(sy,  off);  sy2 += __shfl_down(sy2, off);
    }
    if (lane == 0) { red[w][0] = sx; red[w][1] = sx2; red[w][2] = sy; red[w][3] = sy2; }
    __syncthreads();
    if (tid == 0) {
        double tsx = 0, tsx2 = 0, tsy = 0, tsy2 = 0;
        for (int i = 0; i < 4; ++i) {
            tsx += red[i][0]; tsx2 += red[i][1]; tsy += red[i][2]; tsy2 += red[i][3];
        }
        const double N = (double)NVERT;
        double varx = (tsx2 - tsx * tsx / N) / (N - 1.0);
        double vary = (tsy2 - tsy * tsy / N) / (N - 1.0);
        double sigma = 0.5 * (sqrt(varx) + sqrt(vary));
        const double BD = 1.0 / 63.0;
        if (sigma < BD) sigma = BD;
        const double C2 = pow(2.0, -13.0 / 3.0);   // C^2, C = NV^(-1/6)
        double s2 = sigma * sigma;
        bcast[0] = (float)(-0.5 / C2 / (s2 * 0.69314718055994530942)); // exp2 coeff
        bcast[1] = (float)(1.0 / (2.0 * M_PI * C2) / (s2 * N));        // CF*s^-2/NV
    }
    __syncthreads();
    const float kexp2 = bcast[0];

    // ---- staging constants (round-invariant per thread) ----
    const int   c     = tid & 127;                 // column in es row
    const bool  isX   = (c < 64);
    const float xc    = (float)(c & 63) * (1.0f / 63.0f);
    const int   gbase = tid >> 7;                  // 0 or 1

#define STAGE(JG, BUF)                                                    \
    {                                                                     \
        _Pragma("unroll")                                                 \
        for (int r_ = 0; r_ < 8; ++r_) {                                  \
            int g = r_ * 2 + gbase;                                       \
            float2 t2 = tj[(JG) + g];                                     \
            float tv = isX ? t2.x : t2.y;                                 \
            float d = xc - tv;                                            \
            smem_es[((BUF) * G + g) * 128 + c] = fast_exp2(kexp2 * d * d);\
        }                                                                 \
    }

    // ---- phase 1: double-buffered separable outer-product, 1 barrier/round --
    const int tx = lane >> 3;   // x-block: rows tx*8..tx*8+7
    const int ty = lane & 7;    // y-block: cols ty*8..ty*8+7
    float acc[8][8];
#pragma unroll
    for (int i = 0; i < 8; ++i)
#pragma unroll
        for (int j = 0; j < 8; ++j) acc[i][j] = 0.0f;

    STAGE(0, 0);                                   // prologue: round 0 -> buf 0
    for (int r = 0; r < ROUNDS; ++r) {
        __syncthreads();                           // round r staged; buf r+1 free
        if (r + 1 < ROUNDS) STAGE((r + 1) * G, (r + 1) & 1);
        const float* E = &smem_es[(r & 1) * G * 128];
#pragma unroll
        for (int v = 0; v < 4; ++v) {
            const float* row = &E[((w << 2) + v) * 128];
            float4 ex0 = *reinterpret_cast<const float4*>(&row[tx * 8]);
            float4 ex1 = *reinterpret_cast<const float4*>(&row[tx * 8 + 4]);
            float4 ey0 = *reinterpret_cast<const float4*>(&row[64 + ty * 8]);
            float4 ey1 = *reinterpret_cast<const float4*>(&row[64 + ty * 8 + 4]);
            float ex[8] = {ex0.x, ex0.y, ex0.z, ex0.w, ex1.x, ex1.y, ex1.z, ex1.w};
            float ey[8] = {ey0.x, ey0.y, ey0.z, ey0.w, ey1.x, ey1.y, ey1.z, ey1.w};
#pragma unroll
            for (int i = 0; i < 8; ++i)
#pragma unroll
                for (int j = 0; j < 8; ++j)
                    acc[i][j] = fmaf(ex[i], ey[j], acc[i][j]);
        }
    }

    // ---- phase 2: cross-wave reduction in LDS -> one block partial ----
    __syncthreads();                // all es reads done; safe to alias as gA
    float* gw = (w & 2) ? gB : gA;  // waves 0,1 -> gA; waves 2,3 -> gB
    if (!(w & 1)) {                 // pass 1: waves 0,2 write
#pragma unroll
        for (int i = 0; i < 8; ++i) {
            int base = (tx * 8 + i) * 64 + ty * 8;
            *reinterpret_cast<float4*>(&gw[base]) =
                make_float4(acc[i][0], acc[i][1], acc[i][2], acc[i][3]);
            *reinterpret_cast<float4*>(&gw[base + 4]) =
                make_float4(acc[i][4], acc[i][5], acc[i][6], acc[i][7]);
        }
    }
    __syncthreads();
    if (w & 1) {                    // pass 2: waves 1,3 read-modify-write
#pragma unroll
        for (int i = 0; i < 8; ++i) {
            int base = (tx * 8 + i) * 64 + ty * 8;
            float4 a = *reinterpret_cast<const float4*>(&gw[base]);
            float4 h = *reinterpret_cast<const float4*>(&gw[base + 4]);
            a.x += acc[i][0]; a.y += acc[i][1]; a.z += acc[i][2]; a.w += acc[i][3];
            h.x += acc[i][4]; h.y += acc[i][5]; h.z += acc[i][6]; h.w += acc[i][7];
            *reinterpret_cast<float4*>(&gw[base])     = a;
            *reinterpret_cast<float4*>(&gw[base + 4]) = h;
        }
    }
    __syncthreads();
    // pass 3: all 256 threads sum gA+gB in coalesced float4s, store + total
    float* dst = partials + (size_t)blockIdx.x * NCELL;
    float tsum = 0.f;
#pragma unroll
    for (int q = 0; q < 4; ++q) {
        int f = q * 256 + tid;      // float4 index; lane-consecutive
        float4 a = reinterpret_cast<const float4*>(gA)[f];
        float4 bb = reinterpret_cast<const float4*>(gB)[f];
        float4 r = make_float4(a.x + bb.x, a.y + bb.y, a.z + bb.z, a.w + bb.w);
        reinterpret_cast<float4*>(dst)[f] = r;
        tsum += (r.x + r.y) + (r.z + r.w);
    }
    for (int off = 32; off; off >>= 1) tsum += __shfl_down(tsum, off);
    if (lane == 0) red[w][0] = tsum;
    __syncthreads();
    if (tid == 0)
        totpart[blockIdx.x] = (red[0][0] + red[1][0]) + (red[2][0] + red[3][0]);

    // ---- handshake: make partial+total device-visible, then raise flag ----
    __threadfence();                // writeback: each thread's stores (tid0: totpart)
    __syncthreads();                // all threads fenced before the signal
    if (tid == 0) atomicExch(&flags[blockIdx.x], MAGIC);

    // ---- phase 3: wait for the 64 sibling blocks of batch b, then finish
    //      this block's 64-cell strip [sp*64 .. sp*64+63].
    if (tid < 64) {                 // wave 0: one flag per lane (incl. own)
        const unsigned int* f = flags + (b << 6);
        while (__hip_atomic_load(&f[tid], __ATOMIC_ACQUIRE,
                                 __HIP_MEMORY_SCOPE_AGENT) != MAGIC)
            __builtin_amdgcn_s_sleep(2);
    }
    __syncthreads();
    __threadfence();                // invalidate caches before normal reads

    // wave 0 also fetches totpart concurrently with the strip sums
    float v = (tid < 64) ? totpart[(b << 6) + tid] : 0.0f;

    // wave w sums partials k = w*16 .. w*16+15 for all 64 strip cells
    {
        const float* pb = partials + ((size_t)((b << 6) + (w << 4))) * NCELL
                        + sp * 64 + lane;
        float s0 = 0.f, s1 = 0.f, s2 = 0.f, s3 = 0.f;
#pragma unroll
        for (int k4 = 0; k4 < 4; ++k4) {           // 4 independent chains
            s0 += pb[(size_t)(k4 * 4 + 0) * NCELL];
            s1 += pb[(size_t)(k4 * 4 + 1) * NCELL];
            s2 += pb[(size_t)(k4 * 4 + 2) * NCELL];
            s3 += pb[(size_t)(k4 * 4 + 3) * NCELL];
        }
        fin[w][lane] = (s0 + s1) + (s2 + s3);
    }
    __syncthreads();
    if (tid < 64) {
        for (int off = 32; off; off >>= 1) v += __shfl_down(v, off);
        const float tot   = __shfl(v, 0);
        const float scale = bcast[1];
        const float denom = fmaxf(tot * scale, 1e-5f);
        const float cellv = (fin[0][tid] + fin[1][tid]) + (fin[2][tid] + fin[3][tid]);
        out[b * NCELL + sp * 64 + tid] = (cellv * scale) / denom;
    }
}

// ---------------------------------------------------------------------------
extern "C" void kernel_launch(void* const* d_in, const int* in_sizes, int n_in,
                              void* d_out, int out_size, void* d_ws, size_t ws_size,
                              hipStream_t stream) {
    const float* T = (const float*)d_in[0];   // [B, NV, 2] f32
    // d_in[1] (S) is a deterministic 64x64 meshgrid in [0,1]^2 — derived inline.

    float*        ws       = (float*)d_ws;
    float*        totpart  = ws + TOTPART_OFF;
    unsigned int* flags    = (unsigned int*)(ws + FLAGS_OFF);
    float*        partials = ws + PARTIALS_OFF;

    kde_one<<<BATCH * SPLITS, 256, 0, stream>>>(T, totpart, flags, partials,
                                                (float*)d_out);
}

// Round 10
// 69.475 us; speedup vs baseline: 2.3837x; 2.3837x over previous
//
#include <hip/hip_runtime.h>
#include <math.h>

// Problem constants
#define BATCH 8
#define NVERT 8192
#define NPD   64
#define NCELL 4096             // 64*64 grid cells per batch
#define SPLITS 64              // blocks per batch
#define JPB   (NVERT / SPLITS) // 128 vertices per block
#define KR    32               // vertices per MFMA round (K of one mfma)
#define ROUNDS (JPB / KR)      // 4

#ifndef M_PI
#define M_PI 3.14159265358979323846
#endif

// ws layout (floats)
#define TOTPART_OFF  0         // totpart[512]
#define PARAMS_OFF   1024      // scale[8]
#define PARTIALS_OFF 4096      // 512 * 4096 floats = 8 MB

typedef __attribute__((ext_vector_type(8))) short  bf16x8;
typedef __attribute__((ext_vector_type(4))) float  f32x4;

static __device__ __forceinline__ float fast_exp2(float x) {
#if __has_builtin(__builtin_amdgcn_exp2f)
    return __builtin_amdgcn_exp2f(x);
#else
    return exp2f(x);
#endif
}

// RNE float->bf16 pair pack: low 16 = a, high 16 = b (no inline asm needed).
static __device__ __forceinline__ unsigned int pack_bf16(float a, float b) {
    unsigned int ua = __float_as_uint(a), ub = __float_as_uint(b);
    ua += 0x7fffu + ((ua >> 16) & 1u);
    ub += 0x7fffu + ((ub >> 16) & 1u);
    return (ua >> 16) | (ub & 0xffff0000u);
}

// ---------------------------------------------------------------------------
// Kernel A: sigma + separable KDE via MFMA.
// Grid = BATCH*SPLITS = 512 blocks x 256 threads (4 waves, 2 blocks/CU).
// Per 32-vertex round: the 4 waves cooperatively stage exT[64 gx][32 k] and
// eyT[64 gy][32 k] in bf16 (transposed, padded rows: 40 u16 = 80 B ->
// 2-way banks, 16B-aligned), double-buffered, ONE barrier per round.
// Wave w owns grid-row band [w*16, w*16+16): per round 1 A-frag b128 +
// 4 B-frag b128 + 4x mfma_f32_16x16x32_bf16 (fp32 accumulate).
// Epilogue: write block partial (16 KB) + block total. partials = 8 MB.
// ---------------------------------------------------------------------------
__global__ __launch_bounds__(256) void kde_kernel(const float* __restrict__ T,
                                                  float* __restrict__ params,
                                                  float* __restrict__ totpart,
                                                  float* __restrict__ partials) {
    const int b   = blockIdx.x >> 6;           // / SPLITS
    const int sp  = blockIdx.x & (SPLITS - 1);
    const int j0  = sp * JPB;
    const int tid = threadIdx.x;
    const int w    = tid >> 6;                 // wave id 0..3
    const int lane = tid & 63;

    __shared__ __align__(16) unsigned short exT[2][64][40];  // 10240 B
    __shared__ __align__(16) unsigned short eyT[2][64][40];  // 10240 B
    __shared__ float2 tj[JPB];                 // this block's vertex slice
    __shared__ float  red[4][4];
    __shared__ float  bcast[2];                // kexp2, scale

    // ---- phase 0: sigma over the full batch (redundant per block) ----
    const float4* T4 = reinterpret_cast<const float4*>(T + (size_t)b * NVERT * 2);
    float sx = 0.f, sx2 = 0.f, sy = 0.f, sy2 = 0.f;
    for (int q = tid; q < NVERT / 2; q += 256) {   // 2 vertices per float4
        float4 v = T4[q];
        sx += v.x + v.z;
        sy += v.y + v.w;
        sx2 += v.x * v.x + v.z * v.z;
        sy2 += v.y * v.y + v.w * v.w;
        int local = 2 * q - j0;                    // even when in range
        if ((unsigned)local < (unsigned)JPB)
            *reinterpret_cast<float4*>(&tj[local]) = v;
    }
    for (int off = 32; off; off >>= 1) {
        sx  += __shfl_down(sx,  off);  sx2 += __shfl_down(sx2, off);
        sy  += __shfl_down(sy,  off);  sy2 += __shfl_down(sy2, off);
    }
    if (lane == 0) { red[w][0] = sx; red[w][1] = sx2; red[w][2] = sy; red[w][3] = sy2; }
    __syncthreads();
    if (tid == 0) {
        double tsx = 0, tsx2 = 0, tsy = 0, tsy2 = 0;
        for (int i = 0; i < 4; ++i) {
            tsx += red[i][0]; tsx2 += red[i][1]; tsy += red[i][2]; tsy2 += red[i][3];
        }
        const double N = (double)NVERT;
        double varx = (tsx2 - tsx * tsx / N) / (N - 1.0);
        double vary = (tsy2 - tsy * tsy / N) / (N - 1.0);
        double sigma = 0.5 * (sqrt(varx) + sqrt(vary));
        const double BD = 1.0 / 63.0;
        if (sigma < BD) sigma = BD;
        const double C2 = pow(2.0, -13.0 / 3.0);   // C^2, C = NV^(-1/6)
        double s2 = sigma * sigma;
        bcast[0] = (float)(-0.5 / C2 / (s2 * 0.69314718055994530942)); // exp2 coeff
        bcast[1] = (float)(1.0 / (2.0 * M_PI * C2) / (s2 * N));        // CF*s^-2/NV
        if (sp == 0) params[b] = bcast[1];
    }
    __syncthreads();
    const float kexp2 = bcast[0];

    // ---- staging constants ----
    // Wave w stages plane (w&1: 0=x,1=y), vertex half jh=(w>>1)*16 of each
    // 32-vertex round; lane = gx (0..63). 8 vertex-pairs -> 8 ds_write_b32.
    const float xg   = (float)lane * (1.0f / 63.0f);
    const int   jh   = (w >> 1) << 4;          // 0 or 16
    const bool  isY  = (w & 1);

#define STAGE(R, BUF)                                                       \
    {                                                                       \
        unsigned short (*dstT)[40] = isY ? eyT[BUF] : exT[BUF];             \
        _Pragma("unroll")                                                   \
        for (int jp = 0; jp < 8; ++jp) {                                    \
            int jl = jh + jp * 2;                                           \
            float4 tt = *reinterpret_cast<const float4*>(&tj[(R) * KR + jl]);\
            float tv0 = isY ? tt.y : tt.x;                                  \
            float tv1 = isY ? tt.w : tt.z;                                  \
            float d0 = xg - tv0, d1 = xg - tv1;                             \
            float e0 = fast_exp2(kexp2 * d0 * d0);                          \
            float e1 = fast_exp2(kexp2 * d1 * d1);                          \
            *reinterpret_cast<unsigned int*>(&dstT[lane][jl]) =             \
                pack_bf16(e0, e1);                                          \
        }                                                                   \
    }

    // ---- phase 1: MFMA main loop, double-buffered, 1 barrier per round ----
    const int col16 = lane & 15;
    const int kq    = lane >> 4;               // k-quarter 0..3
    f32x4 acc[4];
#pragma unroll
    for (int ni = 0; ni < 4; ++ni) acc[ni] = (f32x4){0.f, 0.f, 0.f, 0.f};

    STAGE(0, 0);                               // prologue: round 0 -> buf 0
    for (int r = 0; r < ROUNDS; ++r) {
        __syncthreads();                       // round r staged; buf r+1 free
        if (r + 1 < ROUNDS) STAGE(r + 1, (r + 1) & 1);
        const int buf = r & 1;
        // A-frag: lane holds exT[band + col16][kq*8 .. kq*8+7]
        bf16x8 af = *reinterpret_cast<const bf16x8*>(&exT[buf][(w << 4) + col16][kq << 3]);
#pragma unroll
        for (int ni = 0; ni < 4; ++ni) {
            bf16x8 bfr = *reinterpret_cast<const bf16x8*>(&eyT[buf][(ni << 4) + col16][kq << 3]);
            acc[ni] = __builtin_amdgcn_mfma_f32_16x16x32_bf16(af, bfr, acc[ni], 0, 0, 0);
        }
    }

    // ---- phase 2: write block partial + block total ----
    // D layout (m89-verified): col = lane&15, row = (lane>>4)*4 + reg.
    float* dst = partials + (size_t)blockIdx.x * NCELL;
    float tsum = 0.f;
    const int rowbase = (w << 4) + (kq << 2);  // gx of reg r = rowbase + r
#pragma unroll
    for (int ni = 0; ni < 4; ++ni) {
#pragma unroll
        for (int r = 0; r < 4; ++r) {
            dst[(rowbase + r) * 64 + (ni << 4) + col16] = acc[ni][r];
            tsum += acc[ni][r];
        }
    }
    for (int off = 32; off; off >>= 1) tsum += __shfl_down(tsum, off);
    if (lane == 0) red[w][0] = tsum;
    __syncthreads();
    if (tid == 0)
        totpart[blockIdx.x] = (red[0][0] + red[1][0]) + (red[2][0] + red[3][0]);
}

// ---------------------------------------------------------------------------
// Kernel B: sum 64 block-partials/batch, batch total from totpart,
// scale + normalize. Grid = BATCH*32 = 256 blocks x 128 threads (1 cell/thr).
// ---------------------------------------------------------------------------
__global__ __launch_bounds__(128) void finish_kernel(const float* __restrict__ partials,
                                                     const float* __restrict__ totpart,
                                                     const float* __restrict__ params,
                                                     float* __restrict__ out) {
    const int b     = blockIdx.x >> 5;
    const int strip = blockIdx.x & 31;
    const int cell  = strip * 128 + threadIdx.x;
    const float* p  = partials + (size_t)b * SPLITS * NCELL + cell;

    float s[8] = {0.f, 0.f, 0.f, 0.f, 0.f, 0.f, 0.f, 0.f};
#pragma unroll
    for (int k8 = 0; k8 < 8; ++k8)              // 8 independent chains
#pragma unroll
        for (int j = 0; j < 8; ++j)
            s[j] += p[(size_t)(k8 * 8 + j) * NCELL];
    float sum = ((s[0] + s[1]) + (s[2] + s[3])) + ((s[4] + s[5]) + (s[6] + s[7]));

    __shared__ float tot_s;
    if (threadIdx.x < 64) {
        float v = totpart[b * SPLITS + threadIdx.x];
        for (int off = 32; off; off >>= 1) v += __shfl_down(v, off);
        if (threadIdx.x == 0) tot_s = v;
    }
    __syncthreads();

    const float scale = params[b];
    const float denom = fmaxf(tot_s * scale, 1e-5f);
    out[b * NCELL + cell] = (sum * scale) / denom;
}

// ---------------------------------------------------------------------------
extern "C" void kernel_launch(void* const* d_in, const int* in_sizes, int n_in,
                              void* d_out, int out_size, void* d_ws, size_t ws_size,
                              hipStream_t stream) {
    const float* T = (const float*)d_in[0];   // [B, NV, 2] f32
    // d_in[1] (S) is a deterministic 64x64 meshgrid in [0,1]^2 — derived inline.

    float* ws       = (float*)d_ws;
    float* totpart  = ws + TOTPART_OFF;
    float* params   = ws + PARAMS_OFF;
    float* partials = ws + PARTIALS_OFF;

    kde_kernel<<<BATCH * SPLITS, 256, 0, stream>>>(T, params, totpart, partials);
    finish_kernel<<<BATCH * 32, 128, 0, stream>>>(partials, totpart, params,
                                                  (float*)d_out);
}